// Round 4
// baseline (327.121 us; speedup 1.0000x reference)
//
#include <hip/hip_runtime.h>
#include <hip/hip_bf16.h>
#include <math.h>

// GQA forward, round 4: round-3 structure with two fixes:
//  (1) P^T half-exchange now sends the index the PARTNER needs
//      (l5 ? P2[4t] : P2[4t+2]) instead of its own.
//  (2) prep_kernel stray placeholder write (corrupted Wqkv[0..3]) removed.

#define N_SEQ 2048
#define EMB   1024
#define NH    16
#define NKV   4
#define HD    64
#define BATCH 2
#define M_TOT 4096
#define QKV_N 1536

typedef __attribute__((ext_vector_type(8)))  short short8;   // 8 bf16
typedef __attribute__((ext_vector_type(4)))  float f32x4;
typedef __attribute__((ext_vector_type(16))) float f32x16;

__device__ __forceinline__ ushort f2bf(float f) {
    union { __hip_bfloat16 h; ushort u; } cv;
    cv.h = __float2bfloat16(f);
    return cv.u;
}
__device__ __forceinline__ float bf2f(ushort u) {
    union { __hip_bfloat16 h; ushort u; } cv;
    cv.u = u;
    return __bfloat162float(cv.h);
}
__device__ __forceinline__ uint pack2bf(float a, float b) {
    union { __hip_bfloat162 h; uint u; } cv;
    cv.h = __float22bfloat162_rn(float2{a, b});   // a -> low 16, b -> high 16
    return cv.u;
}

// ---------------------------------------------------------------------------
// Fused prep: all f32->bf16 converts + bias pack in 1 launch.
// float4-group index space:
//   [0,1048576) x->xb | +262144 wq | +65536 wk | +65536 wv | +262144 wp
//   | +384 bias pack (f32 passthrough)
// ---------------------------------------------------------------------------
__device__ __forceinline__ void cvt4(const float* __restrict__ s,
                                     ushort* __restrict__ d, long g, long gd) {
    const float4 v = ((const float4*)s)[g];
    ushort4 o;
    o.x = f2bf(v.x); o.y = f2bf(v.y); o.z = f2bf(v.z); o.w = f2bf(v.w);
    ((ushort4*)d)[gd] = o;
}

__global__ __launch_bounds__(256) void prep_kernel(
    const float* __restrict__ x,  const float* __restrict__ wq,
    const float* __restrict__ wk, const float* __restrict__ wv,
    const float* __restrict__ wp, const float* __restrict__ bq,
    const float* __restrict__ bk, const float* __restrict__ bv,
    ushort* __restrict__ xb, ushort* __restrict__ Wqkv,
    ushort* __restrict__ Wproj, float* __restrict__ bqkv)
{
    const long i = (long)blockIdx.x * 256 + threadIdx.x;
    if (i < 1048576) {
        cvt4(x, xb, i, i);
    } else if (i < 1310720) {
        const long g = i - 1048576;
        cvt4(wq, Wqkv, g, g);
    } else if (i < 1376256) {
        const long g = i - 1310720;
        cvt4(wk, Wqkv, g, 262144 + g);
    } else if (i < 1441792) {
        const long g = i - 1376256;
        cvt4(wv, Wqkv, g, 327680 + g);
    } else if (i < 1703936) {
        const long g = i - 1441792;
        cvt4(wp, Wproj, g, g);
    } else if (i < 1704320) {
        const long j = i - 1703936;                       // 0..383 float4 groups
        float4 v;
        if (j < 256)      v = ((const float4*)bq)[j];
        else if (j < 320) v = ((const float4*)bk)[j - 256];
        else              v = ((const float4*)bv)[j - 320];
        ((float4*)bqkv)[j] = v;
    }
}

// ---------------------------------------------------------------------------
// bf16 MFMA GEMM: C[m][n]=sum_k A[m][k]W[n][k]+b[n]  (128x128 tile, BK=32)
// ---------------------------------------------------------------------------
template <bool BF16OUT>
__global__ __launch_bounds__(256) void gemm_mfma_kernel(
    const ushort* __restrict__ A, const ushort* __restrict__ W,
    const float* __restrict__ bias, void* __restrict__ Cout,
    int K, int ldc)
{
    __shared__ ushort As[128 * 40];
    __shared__ ushort Bs[128 * 40];

    const int tid = threadIdx.x;
    const int m0 = blockIdx.y * 128, n0 = blockIdx.x * 128;
    const int w = tid >> 6, lane = tid & 63;
    const int quad = lane >> 4, l16 = lane & 15;
    const int wm = (w & 1) * 64, wn = (w >> 1) * 64;

    f32x4 acc[4][4] = {};

    float bb[4];
#pragma unroll
    for (int j = 0; j < 4; ++j) bb[j] = bias[n0 + wn + j * 16 + l16];

    const int r0 = tid >> 2;
    const int c0 = tid & 3;
    const ushort* Ap = A + (size_t)(m0 + r0) * K + c0 * 8;
    const ushort* Wp = W + (size_t)(n0 + r0) * K + c0 * 8;

    for (int k0 = 0; k0 < K; k0 += 32) {
        const short8 a0 = *(const short8*)(Ap + k0);
        const short8 a1 = *(const short8*)(Ap + (size_t)64 * K + k0);
        const short8 b0 = *(const short8*)(Wp + k0);
        const short8 b1 = *(const short8*)(Wp + (size_t)64 * K + k0);
        __syncthreads();
        *(short8*)&As[r0 * 40 + c0 * 8] = a0;
        *(short8*)&As[(r0 + 64) * 40 + c0 * 8] = a1;
        *(short8*)&Bs[r0 * 40 + c0 * 8] = b0;
        *(short8*)&Bs[(r0 + 64) * 40 + c0 * 8] = b1;
        __syncthreads();

        short8 aF[4], bF[4];
#pragma unroll
        for (int i = 0; i < 4; ++i)
            aF[i] = *(const short8*)&As[(wm + i * 16 + l16) * 40 + quad * 8];
#pragma unroll
        for (int j = 0; j < 4; ++j)
            bF[j] = *(const short8*)&Bs[(wn + j * 16 + l16) * 40 + quad * 8];
#pragma unroll
        for (int i = 0; i < 4; ++i)
#pragma unroll
            for (int j = 0; j < 4; ++j)
                acc[i][j] = __builtin_amdgcn_mfma_f32_16x16x32_bf16(
                    aF[i], bF[j], acc[i][j], 0, 0, 0);
    }

#pragma unroll
    for (int i = 0; i < 4; ++i) {
        const int rowb = m0 + wm + i * 16 + quad * 4;
#pragma unroll
        for (int j = 0; j < 4; ++j) {
            const int col = n0 + wn + j * 16 + l16;
#pragma unroll
            for (int r = 0; r < 4; ++r) {
                const float vv = acc[i][j][r] + bb[j];
                if (BF16OUT)
                    ((ushort*)Cout)[(size_t)(rowb + r) * ldc + col] = f2bf(vv);
                else
                    ((float*)Cout)[(size_t)(rowb + r) * ldc + col] = vv;
            }
        }
    }
}

// ---------------------------------------------------------------------------
// Fused RMSNorm + RoPE for Q and K, wave per head-vector.
// ---------------------------------------------------------------------------
__global__ __launch_bounds__(256) void norm_rope_kernel(
    const ushort* __restrict__ Tq, const float* __restrict__ qn_w,
    const float* __restrict__ kn_w, const float* __restrict__ sinp,
    const float* __restrict__ cosp, ushort* __restrict__ Qb,
    ushort* __restrict__ Kb)
{
    const int gw = (int)(((long)blockIdx.x * 256 + threadIdx.x) >> 6);
    const int lane = threadIdx.x & 63;

    int vec, hshift, colBase;
    const float* nw;
    ushort* dst;
    float outScale;
    if (gw < 65536) {
        vec = gw; hshift = 4; colBase = 0; nw = qn_w; dst = Qb; outScale = 0.125f;
    } else {
        vec = gw - 65536; hshift = 2; colBase = EMB; nw = kn_w; dst = Kb; outScale = 1.0f;
    }

    const int m = vec >> hshift;
    const int h = vec & ((1 << hshift) - 1);
    const int n = m & (N_SEQ - 1);
    const int b = m >> 11;

    const float t = bf2f(Tq[(size_t)m * QKV_N + colBase + h * HD + lane]);
    float s = t * t;
#pragma unroll
    for (int mask = 32; mask; mask >>= 1) s += __shfl_xor(s, mask, 64);
    const float r = rsqrtf(s * (1.0f / 64.0f) + 1e-6f);

    const float tn = t * r * nw[lane];
    const float partner = __shfl_xor(tn, 32, 64);
    const float rot = (lane < 32) ? -partner : partner;
    const float val = (tn * cosp[n * HD + lane] + rot * sinp[n * HD + lane]) * outScale;

    dst[((size_t)((b << hshift) + h) * N_SEQ + n) * HD + lane] = f2bf(val);
}

// ---------------------------------------------------------------------------
// V: Tq [m][1280 + kv*64 + d] -> Vt [(b*KV+kv)*64 + d][n]
// ---------------------------------------------------------------------------
__global__ __launch_bounds__(256) void transpose_v_kernel(
    const ushort* __restrict__ Tq, ushort* __restrict__ Vt)
{
    __shared__ ushort L[64 * 72];
    const int n0 = blockIdx.x * 64;
    const int bkv = blockIdx.y;
    const int b = bkv >> 2, kv = bkv & 3;
    const int tid = threadIdx.x;

#pragma unroll
    for (int it = 0; it < 2; ++it) {
        const int j = tid + it * 256;
        const int r = j >> 3, c = j & 7;
        const short8 v = *(const short8*)&Tq[(size_t)(b * N_SEQ + n0 + r) * QKV_N
                                             + 1280 + kv * HD + c * 8];
        *(short8*)&L[r * 72 + c * 8] = v;
    }
    __syncthreads();
#pragma unroll
    for (int it = 0; it < 2; ++it) {
        const int j = tid + it * 256;
        const int d = j >> 3, c = j & 7;
        short8 o;
#pragma unroll
        for (int e = 0; e < 8; ++e) o[e] = (short)L[(c * 8 + e) * 72 + d];
        *(short8*)&Vt[((size_t)(bkv * HD + d)) * N_SEQ + n0 + c * 8] = o;
    }
}

// ---------------------------------------------------------------------------
// S^T-layout MFMA flash attention (32x32x16).
// Block: 128 q-rows of one (b,h); 4 waves x 32 q-rows; 32 k-tiles of 64 keys.
// S^T = K(A,LDS) x Q^T(B,regs); softmax in C-layout (lane=q-row, keys
// in-register, one shfl_xor(32)); P^T B-frags built in-register; O^T += V^T x P^T.
//
// Fragment bookkeeping (m74/m101 mappings):
//   C/D: col=lane&31 (=q), row=(r&3)+8*(r>>2)+4*l5 (=key within 32)
//   A/B: m(or n)=lane&31, k=l5*8+j
//   Holder lane l5' has keys 8g+4*l5'+2hh+{0,1} packed at P2[2g+hh].
//   Fragment (t) consumer l5 needs: u[0,1] <- l5'=0 @ P2[4t+2*l5],
//                                   u[2,3] <- l5'=1 @ P2[4t+2*l5].
//   => send P2[l5 ? 4t : 4t+2], keep P2[l5 ? 4t+2 : 4t].
// ---------------------------------------------------------------------------
__global__ __launch_bounds__(256) void flash_mfma32_kernel(
    const ushort* __restrict__ Qb, const ushort* __restrict__ Kb,
    const ushort* __restrict__ Vt, ushort* __restrict__ Ob)
{
    __shared__ ushort sm[8704];
    ushort* Ks = sm;            // [64 keys][68]
    ushort* Vs = sm + 4352;     // [64 d][68]

    const int qt = blockIdx.x;              // 0..15 (128 q-rows each)
    const int bh = blockIdx.y;              // b*16+h
    const int b = bh >> 4, h = bh & 15;
    const int kvh = h >> 2;
    const int tid = threadIdx.x;
    const int w = tid >> 6, lane = tid & 63;
    const int l32 = lane & 31, l5 = lane >> 5;

    const ushort* Qg = Qb + ((size_t)bh * N_SEQ + qt * 128 + w * 32) * HD;
    const ushort* Kg = Kb + ((size_t)(b * NKV + kvh) * N_SEQ) * HD;
    const ushort* Vg = Vt + ((size_t)(b * NKV + kvh) * HD) * N_SEQ;

    // Q^T B-frags: qF[c][j] = Q[q0+l32][c*16 + l5*8 + j]
    short8 qF[4];
#pragma unroll
    for (int c = 0; c < 4; ++c)
        qF[c] = *(const short8*)&Qg[(size_t)l32 * HD + c * 16 + l5 * 8];

    f32x16 Oa[2] = {};                       // O^T d-tiles (d 0-31, 32-63)
    float mrow = -3.0e38f, lrow = 0.0f;      // per-lane = per q-row

    const int sr = tid >> 2;                 // staging row 0..63
    const int sc = (tid & 3) * 16;           // staging col (shorts)

    for (int kt = 0; kt < N_SEQ / 64; ++kt) {
        const short8 k0 = *(const short8*)&Kg[(size_t)(kt * 64 + sr) * HD + sc];
        const short8 k1 = *(const short8*)&Kg[(size_t)(kt * 64 + sr) * HD + sc + 8];
        const short8 v0 = *(const short8*)&Vg[(size_t)sr * N_SEQ + kt * 64 + sc];
        const short8 v1 = *(const short8*)&Vg[(size_t)sr * N_SEQ + kt * 64 + sc + 8];
        __syncthreads();                     // prior iter's frag reads done
        *(short8*)&Ks[sr * 68 + sc] = k0;
        *(short8*)&Ks[sr * 68 + sc + 8] = k1;
        *(short8*)&Vs[sr * 68 + sc] = v0;
        *(short8*)&Vs[sr * 68 + sc + 8] = v1;
        __syncthreads();                     // staging visible

        // S^T[s] (32 keys x 32 q-rows)
        f32x16 Sv[2] = {};
#pragma unroll
        for (int s = 0; s < 2; ++s)
#pragma unroll
            for (int c = 0; c < 4; ++c) {
                const short8 kA = *(const short8*)&Ks[(s * 32 + l32) * 68 + c * 16 + l5 * 8];
                Sv[s] = __builtin_amdgcn_mfma_f32_32x32x16_bf16(kA, qF[c], Sv[s], 0, 0, 0);
            }

        // online softmax (keys in-lane + 1 partner shuffle)
        float mx = -3.0e38f;
#pragma unroll
        for (int s = 0; s < 2; ++s)
#pragma unroll
            for (int r = 0; r < 16; ++r) mx = fmaxf(mx, Sv[s][r]);
        mx = fmaxf(mx, __shfl_xor(mx, 32, 64));
        const float mnew = fmaxf(mrow, mx);
        const float alpha = __expf(mrow - mnew);
        mrow = mnew;
        float rs = 0.0f;
#pragma unroll
        for (int s = 0; s < 2; ++s)
#pragma unroll
            for (int r = 0; r < 16; ++r) {
                Sv[s][r] = __expf(Sv[s][r] - mnew);   // Sv becomes P
                rs += Sv[s][r];
            }
        rs += __shfl_xor(rs, 32, 64);
        lrow = lrow * alpha + rs;
#pragma unroll
        for (int t = 0; t < 2; ++t)
#pragma unroll
            for (int r = 0; r < 16; ++r) Oa[t][r] *= alpha;

        // pack P pairs: P2[s][2g+hh] = keys 8g+4*l5+2hh+{0,1} of subtile s
        uint P2[2][8];
#pragma unroll
        for (int s = 0; s < 2; ++s)
#pragma unroll
            for (int g = 0; g < 4; ++g)
#pragma unroll
                for (int hh = 0; hh < 2; ++hh)
                    P2[s][g * 2 + hh] =
                        pack2bf(Sv[s][4 * g + 2 * hh], Sv[s][4 * g + 2 * hh + 1]);

        // P^T B-frags in-register + PV mfma
#pragma unroll
        for (int s = 0; s < 2; ++s)
#pragma unroll
            for (int t = 0; t < 2; ++t) {
                // send what the partner needs; keep what we need
                const uint snd0 = l5 ? P2[s][4 * t + 0] : P2[s][4 * t + 2];
                const uint snd1 = l5 ? P2[s][4 * t + 1] : P2[s][4 * t + 3];
                const uint kp0  = l5 ? P2[s][4 * t + 2] : P2[s][4 * t + 0];
                const uint kp1  = l5 ? P2[s][4 * t + 3] : P2[s][4 * t + 1];
                const uint rcv0 = __shfl_xor(snd0, 32, 64);
                const uint rcv1 = __shfl_xor(snd1, 32, 64);
                union { uint u[4]; short8 s8; } pb;
                pb.u[0] = l5 ? rcv0 : kp0;   // keys +0,1 (from l5'=0)
                pb.u[1] = l5 ? rcv1 : kp1;   // keys +2,3 (from l5'=0)
                pb.u[2] = l5 ? kp0 : rcv0;   // keys +4,5 (from l5'=1)
                pb.u[3] = l5 ? kp1 : rcv1;   // keys +6,7 (from l5'=1)
#pragma unroll
                for (int d2 = 0; d2 < 2; ++d2) {
                    const short8 vA = *(const short8*)
                        &Vs[(d2 * 32 + l32) * 68 + s * 32 + t * 16 + l5 * 8];
                    Oa[d2] = __builtin_amdgcn_mfma_f32_32x32x16_bf16(vA, pb.s8, Oa[d2], 0, 0, 0);
                }
            }
    }

    // epilogue: normalize + transpose O^T -> [q-row][d] via LDS, coalesced out
    __syncthreads();
    ushort* Os = sm;                         // [128][68]
    const float inv = 1.0f / lrow;
#pragma unroll
    for (int d2 = 0; d2 < 2; ++d2)
#pragma unroll
        for (int r = 0; r < 16; ++r) {
            const int d = d2 * 32 + (r & 3) + 8 * (r >> 2) + 4 * l5;
            Os[(w * 32 + l32) * 68 + d] = f2bf(Oa[d2][r] * inv);
        }
    __syncthreads();
    const int row = tid >> 1, c32 = (tid & 1) * 32;
#pragma unroll
    for (int i = 0; i < 4; ++i) {
        const short8 v = *(const short8*)&Os[row * 68 + c32 + i * 8];
        *(short8*)&Ob[((size_t)b * N_SEQ + qt * 128 + row) * EMB + h * HD + c32 + i * 8] = v;
    }
}

// ---------------------------------------------------------------------------
extern "C" void kernel_launch(void* const* d_in, const int* in_sizes, int n_in,
                              void* d_out, int out_size, void* d_ws, size_t ws_size,
                              hipStream_t stream)
{
    const float* x      = (const float*)d_in[0];
    const float* sinp   = (const float*)d_in[1];
    const float* cosp   = (const float*)d_in[2];
    const float* wq_w   = (const float*)d_in[3];
    const float* wq_b   = (const float*)d_in[4];
    const float* wk_w   = (const float*)d_in[5];
    const float* wk_b   = (const float*)d_in[6];
    const float* wv_w   = (const float*)d_in[7];
    const float* wv_b   = (const float*)d_in[8];
    const float* qn_w   = (const float*)d_in[9];
    const float* kn_w   = (const float*)d_in[10];
    const float* proj_w = (const float*)d_in[11];
    const float* proj_b = (const float*)d_in[12];
    float* out = (float*)d_out;

    // workspace layout (ushort elements) — ~39 MB
    ushort* Tq    = (ushort*)d_ws;            // 4096*1536
    ushort* xb    = Tq + 6291456;             // 4096*1024 (reused as Ob)
    ushort* Wqkv  = xb + 4194304;             // 1536*1024
    ushort* Wproj = Wqkv + 1572864;           // 1024*1024
    float*  bqkv  = (float*)(Wproj + 1048576);// 1536
    ushort* Qb    = (ushort*)(bqkv + 1536);   // 2*16*2048*64
    ushort* Kb    = Qb + 4194304;             // 2*4*2048*64
    ushort* Vt    = Kb + 1048576;             // 2*4*64*2048

    prep_kernel<<<6658, 256, 0, stream>>>(x, wq_w, wk_w, wv_w, proj_w,
                                          wq_b, wk_b, wv_b,
                                          xb, Wqkv, Wproj, bqkv);

    gemm_mfma_kernel<true><<<dim3(QKV_N / 128, M_TOT / 128), 256, 0, stream>>>(
        xb, Wqkv, bqkv, Tq, EMB, QKV_N);

    norm_rope_kernel<<<20480, 256, 0, stream>>>(Tq, qn_w, kn_w, sinp, cosp, Qb, Kb);

    transpose_v_kernel<<<dim3(32, 8), 256, 0, stream>>>(Tq, Vt);

    flash_mfma32_kernel<<<dim3(16, 32), 256, 0, stream>>>(Qb, Kb, Vt, xb);

    gemm_mfma_kernel<false><<<dim3(EMB / 128, M_TOT / 128), 256, 0, stream>>>(
        xb, Wproj, proj_b, out, EMB, EMB);
}

// Round 5
// 226.368 us; speedup vs baseline: 1.4451x; 1.4451x over previous
//
#include <hip/hip_runtime.h>
#include <hip/hip_bf16.h>
#include <math.h>

// GQA forward, round 5: barrier-free flash k-loop.
//  - K and V^T stored in MFMA-fragment-order global layouts (written by
//    norm_rope / transpose_v), so flash loads A-frags directly global->VGPR
//    as coalesced 1KB wave loads. No LDS, no __syncthreads in the k-loop.
//  - In-block k-split x2: 4 waves = 2 q-groups x 2 k-halves (16 iters each),
//    merged via LDS at the end. Grid (32,32)=1024 blocks, 16 waves/CU.
//  - __launch_bounds__(256,4) caps VGPR at 128 for 4 waves/SIMD.

#define N_SEQ 2048
#define EMB   1024
#define NH    16
#define NKV   4
#define HD    64
#define BATCH 2
#define M_TOT 4096
#define QKV_N 1536

typedef __attribute__((ext_vector_type(8)))  short short8;   // 8 bf16
typedef __attribute__((ext_vector_type(4)))  float f32x4;
typedef __attribute__((ext_vector_type(16))) float f32x16;

__device__ __forceinline__ ushort f2bf(float f) {
    union { __hip_bfloat16 h; ushort u; } cv;
    cv.h = __float2bfloat16(f);
    return cv.u;
}
__device__ __forceinline__ float bf2f(ushort u) {
    union { __hip_bfloat16 h; ushort u; } cv;
    cv.u = u;
    return __bfloat162float(cv.h);
}
__device__ __forceinline__ uint pack2bf(float a, float b) {
    union { __hip_bfloat162 h; uint u; } cv;
    cv.h = __float22bfloat162_rn(float2{a, b});   // a -> low 16, b -> high 16
    return cv.u;
}

// ---------------------------------------------------------------------------
// Fused prep (unchanged from round 4)
// ---------------------------------------------------------------------------
__device__ __forceinline__ void cvt4(const float* __restrict__ s,
                                     ushort* __restrict__ d, long g, long gd) {
    const float4 v = ((const float4*)s)[g];
    ushort4 o;
    o.x = f2bf(v.x); o.y = f2bf(v.y); o.z = f2bf(v.z); o.w = f2bf(v.w);
    ((ushort4*)d)[gd] = o;
}

__global__ __launch_bounds__(256) void prep_kernel(
    const float* __restrict__ x,  const float* __restrict__ wq,
    const float* __restrict__ wk, const float* __restrict__ wv,
    const float* __restrict__ wp, const float* __restrict__ bq,
    const float* __restrict__ bk, const float* __restrict__ bv,
    ushort* __restrict__ xb, ushort* __restrict__ Wqkv,
    ushort* __restrict__ Wproj, float* __restrict__ bqkv)
{
    const long i = (long)blockIdx.x * 256 + threadIdx.x;
    if (i < 1048576) {
        cvt4(x, xb, i, i);
    } else if (i < 1310720) {
        const long g = i - 1048576;
        cvt4(wq, Wqkv, g, g);
    } else if (i < 1376256) {
        const long g = i - 1310720;
        cvt4(wk, Wqkv, g, 262144 + g);
    } else if (i < 1441792) {
        const long g = i - 1376256;
        cvt4(wv, Wqkv, g, 327680 + g);
    } else if (i < 1703936) {
        const long g = i - 1441792;
        cvt4(wp, Wproj, g, g);
    } else if (i < 1704320) {
        const long j = i - 1703936;
        float4 v;
        if (j < 256)      v = ((const float4*)bq)[j];
        else if (j < 320) v = ((const float4*)bk)[j - 256];
        else              v = ((const float4*)bv)[j - 320];
        ((float4*)bqkv)[j] = v;
    }
}

// ---------------------------------------------------------------------------
// bf16 MFMA GEMM (unchanged): C[m][n]=sum_k A[m][k]W[n][k]+b[n]
// ---------------------------------------------------------------------------
template <bool BF16OUT>
__global__ __launch_bounds__(256) void gemm_mfma_kernel(
    const ushort* __restrict__ A, const ushort* __restrict__ W,
    const float* __restrict__ bias, void* __restrict__ Cout,
    int K, int ldc)
{
    __shared__ ushort As[128 * 40];
    __shared__ ushort Bs[128 * 40];

    const int tid = threadIdx.x;
    const int m0 = blockIdx.y * 128, n0 = blockIdx.x * 128;
    const int w = tid >> 6, lane = tid & 63;
    const int quad = lane >> 4, l16 = lane & 15;
    const int wm = (w & 1) * 64, wn = (w >> 1) * 64;

    f32x4 acc[4][4] = {};

    float bb[4];
#pragma unroll
    for (int j = 0; j < 4; ++j) bb[j] = bias[n0 + wn + j * 16 + l16];

    const int r0 = tid >> 2;
    const int c0 = tid & 3;
    const ushort* Ap = A + (size_t)(m0 + r0) * K + c0 * 8;
    const ushort* Wp = W + (size_t)(n0 + r0) * K + c0 * 8;

    for (int k0 = 0; k0 < K; k0 += 32) {
        const short8 a0 = *(const short8*)(Ap + k0);
        const short8 a1 = *(const short8*)(Ap + (size_t)64 * K + k0);
        const short8 b0 = *(const short8*)(Wp + k0);
        const short8 b1 = *(const short8*)(Wp + (size_t)64 * K + k0);
        __syncthreads();
        *(short8*)&As[r0 * 40 + c0 * 8] = a0;
        *(short8*)&As[(r0 + 64) * 40 + c0 * 8] = a1;
        *(short8*)&Bs[r0 * 40 + c0 * 8] = b0;
        *(short8*)&Bs[(r0 + 64) * 40 + c0 * 8] = b1;
        __syncthreads();

        short8 aF[4], bF[4];
#pragma unroll
        for (int i = 0; i < 4; ++i)
            aF[i] = *(const short8*)&As[(wm + i * 16 + l16) * 40 + quad * 8];
#pragma unroll
        for (int j = 0; j < 4; ++j)
            bF[j] = *(const short8*)&Bs[(wn + j * 16 + l16) * 40 + quad * 8];
#pragma unroll
        for (int i = 0; i < 4; ++i)
#pragma unroll
            for (int j = 0; j < 4; ++j)
                acc[i][j] = __builtin_amdgcn_mfma_f32_16x16x32_bf16(
                    aF[i], bF[j], acc[i][j], 0, 0, 0);
    }

#pragma unroll
    for (int i = 0; i < 4; ++i) {
        const int rowb = m0 + wm + i * 16 + quad * 4;
#pragma unroll
        for (int j = 0; j < 4; ++j) {
            const int col = n0 + wn + j * 16 + l16;
#pragma unroll
            for (int r = 0; r < 4; ++r) {
                const float vv = acc[i][j][r] + bb[j];
                if (BF16OUT)
                    ((ushort*)Cout)[(size_t)(rowb + r) * ldc + col] = f2bf(vv);
                else
                    ((float*)Cout)[(size_t)(rowb + r) * ldc + col] = vv;
            }
        }
    }
}

// ---------------------------------------------------------------------------
// Fused RMSNorm + RoPE. Q -> row-major Qb (as before).
// K -> fragment-order Kf:
//   chunk (bkv, kt, s, c) of 512 shorts; element (l32*16 + l5*8 + j) holds
//   K[key = kt*64 + s*32 + l32][d = c*16 + l5*8 + j].
// ---------------------------------------------------------------------------
__global__ __launch_bounds__(256) void norm_rope_kernel(
    const ushort* __restrict__ Tq, const float* __restrict__ qn_w,
    const float* __restrict__ kn_w, const float* __restrict__ sinp,
    const float* __restrict__ cosp, ushort* __restrict__ Qb,
    ushort* __restrict__ Kf)
{
    const int gw = (int)(((long)blockIdx.x * 256 + threadIdx.x) >> 6);
    const int lane = threadIdx.x & 63;

    const bool isQ = (gw < 65536);
    const int vec = isQ ? gw : gw - 65536;
    const int hshift = isQ ? 4 : 2;
    const int colBase = isQ ? 0 : EMB;
    const float* nw = isQ ? qn_w : kn_w;
    const float outScale = isQ ? 0.125f : 1.0f;

    const int m = vec >> hshift;
    const int h = vec & ((1 << hshift) - 1);
    const int n = m & (N_SEQ - 1);
    const int b = m >> 11;

    const float t = bf2f(Tq[(size_t)m * QKV_N + colBase + h * HD + lane]);
    float s = t * t;
#pragma unroll
    for (int mask = 32; mask; mask >>= 1) s += __shfl_xor(s, mask, 64);
    const float r = rsqrtf(s * (1.0f / 64.0f) + 1e-6f);

    const float tn = t * r * nw[lane];
    const float partner = __shfl_xor(tn, 32, 64);
    const float rot = (lane < 32) ? -partner : partner;
    const float val = (tn * cosp[n * HD + lane] + rot * sinp[n * HD + lane]) * outScale;

    if (isQ) {
        Qb[((size_t)((b << 4) + h) * N_SEQ + n) * HD + lane] = f2bf(val);
    } else {
        const int kt = n >> 6, rr = n & 63, ss = rr >> 5, l32k = rr & 31;
        const int c = lane >> 4, l5k = (lane >> 3) & 1, j = lane & 7;
        Kf[((size_t)(b * NKV + h) * 32 + kt) * 4096
           + (ss * 4 + c) * 512 + l32k * 16 + l5k * 8 + j] = f2bf(val);
    }
}

// ---------------------------------------------------------------------------
// V -> fragment-order Vf:
//   chunk (bkv, kt, s, t, d2) of 512 shorts; element (l32*16 + l5*8 + j) holds
//   V^T[d = d2*32 + l32][key = kt*64 + s*32 + t*16 + l5*8 + j].
// ---------------------------------------------------------------------------
__global__ __launch_bounds__(256) void transpose_v_kernel(
    const ushort* __restrict__ Tq, ushort* __restrict__ Vf)
{
    __shared__ ushort L[64 * 72];
    const int kt = blockIdx.x;             // 0..31 (64 keys each)
    const int n0 = kt * 64;
    const int bkv = blockIdx.y;
    const int b = bkv >> 2, kv = bkv & 3;
    const int tid = threadIdx.x;

#pragma unroll
    for (int it = 0; it < 2; ++it) {
        const int j = tid + it * 256;
        const int r = j >> 3, c = j & 7;
        const short8 v = *(const short8*)&Tq[(size_t)(b * N_SEQ + n0 + r) * QKV_N
                                             + 1280 + kv * HD + c * 8];
        *(short8*)&L[r * 72 + c * 8] = v;
    }
    __syncthreads();
#pragma unroll
    for (int it = 0; it < 2; ++it) {
        const int j = tid + it * 256;
        const int d = j >> 3, c8 = j & 7;
        short8 o;
#pragma unroll
        for (int e = 0; e < 8; ++e) o[e] = (short)L[(c8 * 8 + e) * 72 + d];
        const int ss = c8 >> 2, tt = (c8 >> 1) & 1, l5v = c8 & 1;
        const int d2 = d >> 5, l32v = d & 31;
        *(short8*)&Vf[((size_t)bkv * 32 + kt) * 4096
                      + ((ss * 2 + tt) * 2 + d2) * 512 + l32v * 16 + l5v * 8] = o;
    }
}

// ---------------------------------------------------------------------------
// Barrier-free S^T-layout MFMA flash attention with in-block k-split.
// Grid (32 qt, 32 bh); block 256 = 4 waves: wave w = q-group (w&1, 32 rows)
// x k-half (w>>1, 16 k-tiles of 64 keys). K/V A-frags loaded directly from
// fragment-order global (coalesced 1KB wave loads, L2-resident). Q^T B-frags
// in regs. Softmax in C-layout (lane = q-row). P^T B-frags in-register.
// End: k-halves merged via LDS (m,l,O), epilogue transpose, coalesced store.
// ---------------------------------------------------------------------------
__global__ __launch_bounds__(256, 4) void flash_mfma32_kernel(
    const ushort* __restrict__ Qb, const ushort* __restrict__ Kf,
    const ushort* __restrict__ Vf, ushort* __restrict__ Ob)
{
    __shared__ float fsm[4352];            // 2 x (2048 O + 64 m + 64 l) = 17.4KB

    const int qt = blockIdx.x;             // 0..31 (64 q-rows)
    const int bh = blockIdx.y;
    const int b = bh >> 4, h = bh & 15;
    const int kvh = h >> 2;
    const int tid = threadIdx.x;
    const int w = tid >> 6, lane = tid & 63;
    const int l32 = lane & 31, l5 = lane >> 5;
    const int qg = w & 1;                  // q-group within block
    const int kh = w >> 1;                 // k-half

    const ushort* Qg = Qb + ((size_t)bh * N_SEQ + qt * 64 + qg * 32) * HD;
    const size_t kvbase = (size_t)(b * NKV + kvh) * (32 * 4096);
    const ushort* Kp = Kf + kvbase;
    const ushort* Vp = Vf + kvbase;
    const int loff = l32 * 16 + l5 * 8;

    // Q^T B-frags: qF[c][j] = Q[q0+l32][c*16 + l5*8 + j]
    short8 qF[4];
#pragma unroll
    for (int c = 0; c < 4; ++c)
        qF[c] = *(const short8*)&Qg[(size_t)l32 * HD + c * 16 + l5 * 8];

    f32x16 Oa[2] = {};                     // O^T d-tiles (d 0-31, 32-63)
    float mrow = -3.0e38f, lrow = 0.0f;

    for (int i = 0; i < 16; ++i) {
        const int kt = kh * 16 + i;
        const ushort* Kt = Kp + kt * 4096;
        const ushort* Vt = Vp + kt * 4096;

        // direct global->reg fragment loads (coalesced, L2-hit)
        short8 kT[2][4];
#pragma unroll
        for (int s = 0; s < 2; ++s)
#pragma unroll
            for (int c = 0; c < 4; ++c)
                kT[s][c] = *(const short8*)&Kt[(s * 4 + c) * 512 + loff];
        short8 vT[2][2][2];
#pragma unroll
        for (int s = 0; s < 2; ++s)
#pragma unroll
            for (int t = 0; t < 2; ++t)
#pragma unroll
                for (int d2 = 0; d2 < 2; ++d2)
                    vT[s][t][d2] = *(const short8*)&Vt[((s * 2 + t) * 2 + d2) * 512 + loff];

        // S^T (32 keys x 32 q-rows) per key-subtile s
        f32x16 Sv[2] = {};
#pragma unroll
        for (int s = 0; s < 2; ++s)
#pragma unroll
            for (int c = 0; c < 4; ++c)
                Sv[s] = __builtin_amdgcn_mfma_f32_32x32x16_bf16(kT[s][c], qF[c], Sv[s], 0, 0, 0);

        // online softmax (keys in-lane + 1 partner shuffle)
        float mx = -3.0e38f;
#pragma unroll
        for (int s = 0; s < 2; ++s)
#pragma unroll
            for (int r = 0; r < 16; ++r) mx = fmaxf(mx, Sv[s][r]);
        mx = fmaxf(mx, __shfl_xor(mx, 32, 64));
        const float mnew = fmaxf(mrow, mx);
        const float alpha = __expf(mrow - mnew);
        mrow = mnew;
        float rs = 0.0f;
#pragma unroll
        for (int s = 0; s < 2; ++s)
#pragma unroll
            for (int r = 0; r < 16; ++r) {
                Sv[s][r] = __expf(Sv[s][r] - mnew);
                rs += Sv[s][r];
            }
        rs += __shfl_xor(rs, 32, 64);
        lrow = lrow * alpha + rs;
#pragma unroll
        for (int t = 0; t < 2; ++t)
#pragma unroll
            for (int r = 0; r < 16; ++r) Oa[t][r] *= alpha;

        // pack P pairs: P2[s][2g+hh] = keys 8g+4*l5+2hh+{0,1} of subtile s
        uint P2[2][8];
#pragma unroll
        for (int s = 0; s < 2; ++s)
#pragma unroll
            for (int g = 0; g < 4; ++g)
#pragma unroll
                for (int hh = 0; hh < 2; ++hh)
                    P2[s][g * 2 + hh] =
                        pack2bf(Sv[s][4 * g + 2 * hh], Sv[s][4 * g + 2 * hh + 1]);

        // P^T B-frags in-register + PV mfma
#pragma unroll
        for (int s = 0; s < 2; ++s)
#pragma unroll
            for (int t = 0; t < 2; ++t) {
                const uint snd0 = l5 ? P2[s][4 * t + 0] : P2[s][4 * t + 2];
                const uint snd1 = l5 ? P2[s][4 * t + 1] : P2[s][4 * t + 3];
                const uint kp0  = l5 ? P2[s][4 * t + 2] : P2[s][4 * t + 0];
                const uint kp1  = l5 ? P2[s][4 * t + 3] : P2[s][4 * t + 1];
                const uint rcv0 = __shfl_xor(snd0, 32, 64);
                const uint rcv1 = __shfl_xor(snd1, 32, 64);
                union { uint u[4]; short8 s8; } pb;
                pb.u[0] = l5 ? rcv0 : kp0;
                pb.u[1] = l5 ? rcv1 : kp1;
                pb.u[2] = l5 ? kp0 : rcv0;
                pb.u[3] = l5 ? kp1 : rcv1;
#pragma unroll
                for (int d2 = 0; d2 < 2; ++d2)
                    Oa[d2] = __builtin_amdgcn_mfma_f32_32x32x16_bf16(
                        vT[s][t][d2], pb.s8, Oa[d2], 0, 0, 0);
            }
    }

    // ---- merge the two k-halves (wave pairs w, w+2 share q-rows) ----
    float* buf = fsm + qg * 2176;
    if (kh == 1) {
#pragma unroll
        for (int d2 = 0; d2 < 2; ++d2)
#pragma unroll
            for (int r = 0; r < 16; ++r)
                buf[(d2 * 16 + r) * 64 + lane] = Oa[d2][r];
        buf[2048 + lane] = mrow;
        buf[2112 + lane] = lrow;
    }
    __syncthreads();

    if (kh == 0) {
        const float mb = buf[2048 + lane];
        const float lb = buf[2112 + lane];
        const float M = fmaxf(mrow, mb);
        const float ea = __expf(mrow - M), eb = __expf(mb - M);
        lrow = lrow * ea + lb * eb;
#pragma unroll
        for (int d2 = 0; d2 < 2; ++d2)
#pragma unroll
            for (int r = 0; r < 16; ++r)
                Oa[d2][r] = Oa[d2][r] * ea + buf[(d2 * 16 + r) * 64 + lane] * eb;
    }
    __syncthreads();                        // merge reads done before Os reuse

    // ---- epilogue: normalize + transpose to row-major via LDS ----
    ushort* Os = (ushort*)fsm;              // [64][68]
    if (kh == 0) {
        const float inv = 1.0f / lrow;
#pragma unroll
        for (int d2 = 0; d2 < 2; ++d2)
#pragma unroll
            for (int r = 0; r < 16; ++r) {
                const int d = d2 * 32 + (r & 3) + 8 * (r >> 2) + 4 * l5;
                Os[(qg * 32 + l32) * 68 + d] = f2bf(Oa[d2][r] * inv);
            }
    }
    __syncthreads();

    const int row = tid >> 2, cc = (tid & 3) * 16;
#pragma unroll
    for (int i = 0; i < 2; ++i) {
        const short8 v = *(const short8*)&Os[row * 68 + cc + i * 8];
        *(short8*)&Ob[((size_t)b * N_SEQ + qt * 64 + row) * EMB + h * HD + cc + i * 8] = v;
    }
}

// ---------------------------------------------------------------------------
extern "C" void kernel_launch(void* const* d_in, const int* in_sizes, int n_in,
                              void* d_out, int out_size, void* d_ws, size_t ws_size,
                              hipStream_t stream)
{
    const float* x      = (const float*)d_in[0];
    const float* sinp   = (const float*)d_in[1];
    const float* cosp   = (const float*)d_in[2];
    const float* wq_w   = (const float*)d_in[3];
    const float* wq_b   = (const float*)d_in[4];
    const float* wk_w   = (const float*)d_in[5];
    const float* wk_b   = (const float*)d_in[6];
    const float* wv_w   = (const float*)d_in[7];
    const float* wv_b   = (const float*)d_in[8];
    const float* qn_w   = (const float*)d_in[9];
    const float* kn_w   = (const float*)d_in[10];
    const float* proj_w = (const float*)d_in[11];
    const float* proj_b = (const float*)d_in[12];
    float* out = (float*)d_out;

    // workspace layout (ushort elements) — ~39 MB
    ushort* Tq    = (ushort*)d_ws;            // 4096*1536
    ushort* xb    = Tq + 6291456;             // 4096*1024 (reused as Ob)
    ushort* Wqkv  = xb + 4194304;             // 1536*1024
    ushort* Wproj = Wqkv + 1572864;           // 1024*1024
    float*  bqkv  = (float*)(Wproj + 1048576);// 1536
    ushort* Qb    = (ushort*)(bqkv + 1536);   // 2*16*2048*64
    ushort* Kf    = Qb + 4194304;             // frag-order K, 1048576
    ushort* Vf    = Kf + 1048576;             // frag-order V^T, 1048576

    prep_kernel<<<6658, 256, 0, stream>>>(x, wq_w, wk_w, wv_w, proj_w,
                                          wq_b, wk_b, wv_b,
                                          xb, Wqkv, Wproj, bqkv);

    gemm_mfma_kernel<true><<<dim3(QKV_N / 128, M_TOT / 128), 256, 0, stream>>>(
        xb, Wqkv, bqkv, Tq, EMB, QKV_N);

    norm_rope_kernel<<<20480, 256, 0, stream>>>(Tq, qn_w, kn_w, sinp, cosp, Qb, Kf);

    transpose_v_kernel<<<dim3(32, 8), 256, 0, stream>>>(Tq, Vf);

    flash_mfma32_kernel<<<dim3(32, 32), 256, 0, stream>>>(Qb, Kf, Vf, xb);

    gemm_mfma_kernel<false><<<dim3(EMB / 128, M_TOT / 128), 256, 0, stream>>>(
        xb, Wproj, proj_b, out, EMB, EMB);
}